// Round 3
// baseline (118.077 us; speedup 1.0000x reference)
//
#include <hip/hip_runtime.h>
#include <stdint.h>

// y[m][n] = scales[n] * sum_k x[m][k]*W[n][k] + bias[n]
// M=128, K=4096, N=11008. x fp32; W int8-valued int32 [N][K]; out fp32.
//
// Round-3 structure (latency-bound fix: TLP + barrier-free pipelining):
//   pack_x: x fp32 -> bf16 in MFMA A-frag order into ws (1 MiB, L2-hot).
//   gemm1w: ONE WAVE per block, BM=32 x BN=32, K split 4 ways.
//           grid 344 x 4 x 4 = 5504 independent waves (~12 resident/CU).
//           No LDS, no barriers: A frags loaded bf16 direct from xp,
//           B loaded int32 -> exact in-reg convert to bf16, 1-chunk-deep
//           named double-buffer so the compiler emits a counted-vmcnt
//           load/MFMA stream. Partials fp32 -> ws.
//   reduce: out = scales*(sum of ks partials) + bias (deterministic).

#define M_ROWS 128
#define K_DIM  4096
#define N_DIM  11008
#define CHUNKS 64                       // K chunks of 64
#define NT     (N_DIM / 32)             // 344 n-tiles
#define XP_BYTES (M_ROWS * K_DIM * 2)   // 1 MiB packed bf16 x
#define PART_ELEMS ((size_t)M_ROWS * (size_t)N_DIM)

typedef __attribute__((ext_vector_type(8))) short bf16x8;
typedef __attribute__((ext_vector_type(4))) float f32x4;

__device__ __forceinline__ unsigned bf16_rn(float f) {
  unsigned u = __float_as_uint(f);
  return (u + 0x7FFFu + ((u >> 16) & 1u)) >> 16;   // round-to-nearest-even
}
// pack two small ints (exact in bf16) into one dword of 2xbf16 (truncate = exact)
__device__ __forceinline__ unsigned pk2(int a, int b) {
  return (__float_as_uint((float)b) & 0xFFFF0000u) | (__float_as_uint((float)a) >> 16);
}

// ---------------- pack x: fp32 -> bf16 in A-frag order ----------------
// Chunk kk = 16 KiB: 16B unit u = (mf*2 + s)*64 + lane
// frag (mf,s): lane l holds x[16*mf + (l&15)][kk*64 + s*32 + 8*(l>>4) + j]
__global__ __launch_bounds__(256) void pack_x_kernel(
    const float* __restrict__ x, unsigned short* __restrict__ xp) {
  int tid  = blockIdx.x * 256 + threadIdx.x;   // 65536 threads
  int lane = tid & 63;
  int h    = (tid >> 6) & 1;
  int mf   = (tid >> 7) & 7;
  int kk   = tid >> 10;
  int m     = mf * 16 + (lane & 15);
  int kbase = kk * 64 + h * 32 + ((lane >> 4) * 8);
  const float* src = x + (size_t)m * K_DIM + kbase;
  float4 f0 = *(const float4*)(src);
  float4 f1 = *(const float4*)(src + 4);
  float v[8] = {f0.x, f0.y, f0.z, f0.w, f1.x, f1.y, f1.z, f1.w};
  unsigned po[4];
#pragma unroll
  for (int i = 0; i < 4; ++i)
    po[i] = bf16_rn(v[2 * i]) | (bf16_rn(v[2 * i + 1]) << 16);
  *(uint4*)(xp + (size_t)tid * 8) = *(uint4*)po;
}

// ---------------- single-wave GEMM ----------------
struct PBuf { uint4 w[8]; bf16x8 a[4]; };

__global__ __launch_bounds__(64, 3) void gemm1w_kernel(
    const unsigned short* __restrict__ xp,
    const int* __restrict__ wq,
    const float* __restrict__ scales,
    const float* __restrict__ bias,
    float* __restrict__ dst,          // ks==1: out, else partials
    int ks) {
  const int lane = threadIdx.x;        // 0..63
  const int nt   = blockIdx.x;         // 0..343
  const int my   = blockIdx.y;         // 0..3 (M strip of 32)
  const int kz   = blockIdx.z;         // 0..ks-1
  const int cpb  = CHUNKS / ks;        // chunks per block (even)
  const int kk0  = kz * cpb;
  const size_t n0 = (size_t)nt * 32;
  const int l15 = lane & 15, lh = lane >> 4;

  // A: byte addr = kk*16384 + my*4096 + (mf*2+s)*1024 + lane*16
  const char* aptr = (const char*)xp + (size_t)kk0 * 16384 + my * 4096 + lane * 16;
  // B: row n0 + nf*16 + l15, k = kk*64 + s*32 + lh*8  (8 ints per frag-lane)
  const int* bptr0 = wq + (n0 + (size_t)l15) * K_DIM + (size_t)kk0 * 64 + lh * 8;
  const int* bptr1 = bptr0 + (size_t)16 * K_DIM;

  f32x4 acc[2][2];
  {
    f32x4 z = {0.f, 0.f, 0.f, 0.f};
#pragma unroll
    for (int i = 0; i < 2; ++i)
#pragma unroll
      for (int j = 0; j < 2; ++j) acc[i][j] = z;
  }

  auto LOAD = [&](int t, PBuf& P) {
    const char* ac = aptr + (size_t)t * 16384;
#pragma unroll
    for (int f = 0; f < 4; ++f)
      P.a[f] = *(const bf16x8*)(ac + f * 1024);
#pragma unroll
    for (int nf = 0; nf < 2; ++nf)
#pragma unroll
      for (int s = 0; s < 2; ++s) {
        const int* bp = (nf ? bptr1 : bptr0) + t * 64 + s * 32;
        P.w[(nf * 2 + s) * 2 + 0] = *(const uint4*)bp;
        P.w[(nf * 2 + s) * 2 + 1] = *(const uint4*)(bp + 4);
      }
  };
  auto COMPUTE = [&](PBuf& P) {
#pragma unroll
    for (int nf = 0; nf < 2; ++nf)
#pragma unroll
      for (int s = 0; s < 2; ++s) {
        uint4 lo = P.w[(nf * 2 + s) * 2 + 0];
        uint4 hi = P.w[(nf * 2 + s) * 2 + 1];
        union { unsigned u[4]; bf16x8 b; } cv;
        cv.u[0] = pk2((int)lo.x, (int)lo.y);
        cv.u[1] = pk2((int)lo.z, (int)lo.w);
        cv.u[2] = pk2((int)hi.x, (int)hi.y);
        cv.u[3] = pk2((int)hi.z, (int)hi.w);
#pragma unroll
        for (int mf = 0; mf < 2; ++mf)
          acc[mf][nf] = __builtin_amdgcn_mfma_f32_16x16x32_bf16(
              P.a[mf * 2 + s], cv.b, acc[mf][nf], 0, 0, 0);
      }
  };

  PBuf A, B;
  LOAD(0, A);
#pragma unroll 1
  for (int tt = 0; tt < cpb; tt += 2) {
    LOAD(tt + 1, B);          // cpb even: tt+1 < cpb always
    COMPUTE(A);
    if (tt + 2 < cpb) LOAD(tt + 2, A);
    COMPUTE(B);
  }

  // epilogue: m = my*32 + mf*16 + lh*4 + r ; n = n0 + nf*16 + l15
  if (ks == 1) {
#pragma unroll
    for (int nf = 0; nf < 2; ++nf) {
      const size_t n = n0 + (size_t)(nf * 16 + l15);
      const float sc = scales[n], bi = bias[n];
#pragma unroll
      for (int mf = 0; mf < 2; ++mf) {
        const int mb = my * 32 + mf * 16 + lh * 4;
#pragma unroll
        for (int r = 0; r < 4; ++r)
          dst[(size_t)(mb + r) * N_DIM + n] = sc * acc[mf][nf][r] + bi;
      }
    }
  } else {
    float* pb = dst + (size_t)kz * PART_ELEMS;
#pragma unroll
    for (int nf = 0; nf < 2; ++nf) {
      const size_t n = n0 + (size_t)(nf * 16 + l15);
#pragma unroll
      for (int mf = 0; mf < 2; ++mf) {
        const int mb = my * 32 + mf * 16 + lh * 4;
#pragma unroll
        for (int r = 0; r < 4; ++r)
          pb[(size_t)(mb + r) * N_DIM + n] = acc[mf][nf][r];
      }
    }
  }
}

// ---------------- combine partials + epilogue ----------------
__global__ __launch_bounds__(256) void reduce_kernel(
    const float* __restrict__ part, const float* __restrict__ scales,
    const float* __restrict__ bias, float* __restrict__ out, int ks) {
  const int m = blockIdx.y;
  const int c4 = blockIdx.x * 256 + threadIdx.x;
  if (c4 >= N_DIM / 4) return;
  const size_t n = (size_t)c4 * 4;
  const float* p = part + (size_t)m * N_DIM + n;
  float4 s = *(const float4*)(p);
  for (int z = 1; z < ks; ++z) {
    float4 q = *(const float4*)(p + (size_t)z * PART_ELEMS);
    s.x += q.x; s.y += q.y; s.z += q.z; s.w += q.w;
  }
  float4 sc = *(const float4*)(scales + n);
  float4 bi = *(const float4*)(bias + n);
  float4 r;
  r.x = sc.x * s.x + bi.x;
  r.y = sc.y * s.y + bi.y;
  r.z = sc.z * s.z + bi.z;
  r.w = sc.w * s.w + bi.w;
  *(float4*)(out + (size_t)m * N_DIM + n) = r;
}

// ---------------- insurance path if ws is tiny ----------------
__global__ __launch_bounds__(256) void naive_kernel(
    const float* __restrict__ x, const int* __restrict__ wq,
    const float* __restrict__ scales, const float* __restrict__ bias,
    float* __restrict__ out) {
  const int n = blockIdx.x * 256 + threadIdx.x;
  const int m = blockIdx.y;
  const float* xr = x + (size_t)m * K_DIM;
  const int* wr = wq + (size_t)n * K_DIM;
  float s = 0.f;
  for (int k = 0; k < K_DIM; k += 4) {
    float4 xv = *(const float4*)(xr + k);
    int4  wv = *(const int4*)(wr + k);
    s += xv.x * (float)wv.x + xv.y * (float)wv.y +
         xv.z * (float)wv.z + xv.w * (float)wv.w;
  }
  out[(size_t)m * N_DIM + n] = scales[n] * s + bias[n];
}

extern "C" void kernel_launch(void* const* d_in, const int* in_sizes, int n_in,
                              void* d_out, int out_size, void* d_ws, size_t ws_size,
                              hipStream_t stream) {
  const float* x      = (const float*)d_in[0];
  const int* wq       = (const int*)d_in[1];
  const float* scales = (const float*)d_in[2];
  const float* bias   = (const float*)d_in[3];
  float* out          = (float*)d_out;

  const size_t need4 = (size_t)XP_BYTES + 4 * PART_ELEMS * sizeof(float);
  const size_t need2 = (size_t)XP_BYTES + 2 * PART_ELEMS * sizeof(float);
  int ks = (ws_size >= need4) ? 4 : (ws_size >= need2) ? 2
         : (ws_size >= (size_t)XP_BYTES) ? 1 : 0;
  if (ks == 0) {
    naive_kernel<<<dim3(N_DIM / 256, M_ROWS), 256, 0, stream>>>(x, wq, scales, bias, out);
    return;
  }
  unsigned short* xp = (unsigned short*)d_ws;
  float* part        = (float*)((char*)d_ws + XP_BYTES);

  pack_x_kernel<<<256, 256, 0, stream>>>(x, xp);
  gemm1w_kernel<<<dim3(NT, 4, ks), 64, 0, stream>>>(
      xp, wq, scales, bias, ks == 1 ? out : part, ks);
  if (ks > 1)
    reduce_kernel<<<dim3((N_DIM / 4 + 255) / 256, M_ROWS), 256, 0, stream>>>(
        part, scales, bias, out, ks);
}

// Round 4
// 65.471 us; speedup vs baseline: 1.8035x; 1.8035x over previous
//
#include <hip/hip_runtime.h>
#include <stdint.h>

// y[m][n] = scales[n] * sum_k x[m][k]*W[n][k] + bias[n]
// M=128, K=4096, N=11008. x fp32; W int8-valued int32 [N][K]; out fp32.
//
// Round-4 structure (L3-BW fix: weights cross L3 exactly ONCE):
//   pack_x: x fp32 -> bf16 in MFMA A-frag order into ws (1 MiB, L2-resident).
//   gemm1w: ONE WAVE per block, BM=128 (FULL M) x BN=16, K split 4 ways.
//           B read once total (180 MB ~= L3 floor ~33us); A re-read from L2.
//           grid 688 x 4 = 2752 waves, VGPR<=168 -> 3/SIMD -> ALL resident.
//           No LDS, no barriers. B int32 -> bf16 via 2x v_cvt_f32_i32 +
//           v_perm_b32 (exact). B regs double-buffered one chunk ahead.
//   reduce: out = scales*(sum of 4 partials) + bias (deterministic).

#define M_ROWS 128
#define K_DIM  4096
#define N_DIM  11008
#define CHUNKS 64                       // K chunks of 64
#define NT16   (N_DIM / 16)             // 688 n-tiles
#define XP_BYTES (M_ROWS * K_DIM * 2)   // 1 MiB packed bf16 x
#define PART_ELEMS ((size_t)M_ROWS * (size_t)N_DIM)

typedef __attribute__((ext_vector_type(8))) short bf16x8;
typedef __attribute__((ext_vector_type(4))) float f32x4;

__device__ __forceinline__ unsigned bf16_rn(float f) {
  unsigned u = __float_as_uint(f);
  return (u + 0x7FFFu + ((u >> 16) & 1u)) >> 16;   // round-to-nearest-even
}
// two exact int->f32, pack top halves: {lo.b2,lo.b3,hi.b2,hi.b3} (1 v_perm_b32)
__device__ __forceinline__ unsigned pk2(int a, int b) {
  unsigned lo = __float_as_uint((float)a), hi = __float_as_uint((float)b);
#if __has_builtin(__builtin_amdgcn_perm)
  return __builtin_amdgcn_perm(hi, lo, 0x07060302u);
#else
  return (hi & 0xFFFF0000u) | (lo >> 16);
#endif
}

// ---------------- pack x: fp32 -> bf16 in A-frag order ----------------
// Chunk kk = 16 KiB: 16B unit u = (mf*2 + s)*64 + lane
// frag (mf,s): lane l holds x[16*mf + (l&15)][kk*64 + s*32 + 8*(l>>4) + j]
__global__ __launch_bounds__(256) void pack_x_kernel(
    const float* __restrict__ x, unsigned short* __restrict__ xp) {
  int tid  = blockIdx.x * 256 + threadIdx.x;   // 65536 threads
  int lane = tid & 63;
  int h    = (tid >> 6) & 1;
  int mf   = (tid >> 7) & 7;
  int kk   = tid >> 10;
  int m     = mf * 16 + (lane & 15);
  int kbase = kk * 64 + h * 32 + ((lane >> 4) * 8);
  const float* src = x + (size_t)m * K_DIM + kbase;
  float4 f0 = *(const float4*)(src);
  float4 f1 = *(const float4*)(src + 4);
  float v[8] = {f0.x, f0.y, f0.z, f0.w, f1.x, f1.y, f1.z, f1.w};
  unsigned po[4];
#pragma unroll
  for (int i = 0; i < 4; ++i)
    po[i] = bf16_rn(v[2 * i]) | (bf16_rn(v[2 * i + 1]) << 16);
  *(uint4*)(xp + (size_t)tid * 8) = *(uint4*)po;
}

// ---------------- single-wave GEMM: BM=128 x BN=16 ----------------
struct BReg { uint4 v[4]; };   // one chunk of B per lane: 16 ints

__global__ __launch_bounds__(64, 3) void gemm1w_kernel(
    const unsigned short* __restrict__ xp,
    const int* __restrict__ wq,
    const float* __restrict__ scales,
    const float* __restrict__ bias,
    float* __restrict__ dst,          // ks==1: out, else partials
    int ks) {
  const int lane = threadIdx.x;       // 0..63
  const int nt   = blockIdx.x;        // 0..687
  const int kz   = blockIdx.y;        // 0..ks-1
  const int cpb  = CHUNKS / ks;       // chunks per block (even for ks=2,4)
  const int kk0  = kz * cpb;
  const size_t n0 = (size_t)nt * 16;
  const int l15 = lane & 15, lh = lane >> 4;

  // A: byte addr = (kk0+t)*16384 + (mf*2+s)*1024 + lane*16   (full M per wave)
  const char* aptr = (const char*)xp + (size_t)kk0 * 16384 + lane * 16;
  // B: row n0 + l15; ints at (kk0+t)*64 + s*32 + lh*8 .. +8
  const int* bptr = wq + (n0 + (size_t)l15) * K_DIM + (size_t)kk0 * 64 + lh * 8;

  f32x4 acc[8];
  {
    f32x4 z = {0.f, 0.f, 0.f, 0.f};
#pragma unroll
    for (int i = 0; i < 8; ++i) acc[i] = z;
  }

  auto LOADB = [&](int t, BReg& R) {
    const int* bp = bptr + t * 64;
#pragma unroll
    for (int s = 0; s < 2; ++s) {
      R.v[s * 2]     = *(const uint4*)(bp + s * 32);
      R.v[s * 2 + 1] = *(const uint4*)(bp + s * 32 + 4);
    }
  };
  auto CONVCOMP = [&](int t, BReg& R) {
    bf16x8 cv[2];
#pragma unroll
    for (int s = 0; s < 2; ++s) {
      union { unsigned u[4]; bf16x8 b; } c;
      c.u[0] = pk2((int)R.v[s * 2].x,     (int)R.v[s * 2].y);
      c.u[1] = pk2((int)R.v[s * 2].z,     (int)R.v[s * 2].w);
      c.u[2] = pk2((int)R.v[s * 2 + 1].x, (int)R.v[s * 2 + 1].y);
      c.u[3] = pk2((int)R.v[s * 2 + 1].z, (int)R.v[s * 2 + 1].w);
      cv[s] = c.b;
    }
    const char* ac = aptr + (size_t)t * 16384;
#pragma unroll
    for (int h = 0; h < 2; ++h) {           // two groups of 4 M-frags
      bf16x8 a[8];
#pragma unroll
      for (int q = 0; q < 8; ++q)
        a[q] = *(const bf16x8*)(ac + (h * 8 + q) * 1024);
#pragma unroll
      for (int mf = 0; mf < 4; ++mf)
#pragma unroll
        for (int s = 0; s < 2; ++s)
          acc[h * 4 + mf] = __builtin_amdgcn_mfma_f32_16x16x32_bf16(
              a[mf * 2 + s], cv[s], acc[h * 4 + mf], 0, 0, 0);
    }
  };

  BReg R0, R1;
  LOADB(0, R0);
#pragma unroll 1
  for (int tt = 0; tt < cpb; tt += 2) {
    LOADB(tt + 1, R1);              // cpb even -> always valid
    CONVCOMP(tt, R0);
    if (tt + 2 < cpb) LOADB(tt + 2, R0);
    CONVCOMP(tt + 1, R1);
  }

  // epilogue: m = i*16 + lh*4 + r (i = acc index), n = n0 + l15
  if (ks == 1) {
    const size_t n = n0 + (size_t)l15;
    const float sc = scales[n], bi = bias[n];
#pragma unroll
    for (int i = 0; i < 8; ++i) {
      const int mb = i * 16 + lh * 4;
#pragma unroll
      for (int r = 0; r < 4; ++r)
        dst[(size_t)(mb + r) * N_DIM + n] = sc * acc[i][r] + bi;
    }
  } else {
    float* pb = dst + (size_t)kz * PART_ELEMS + n0 + l15;
#pragma unroll
    for (int i = 0; i < 8; ++i) {
      const int mb = i * 16 + lh * 4;
#pragma unroll
      for (int r = 0; r < 4; ++r)
        pb[(size_t)(mb + r) * N_DIM] = acc[i][r];
    }
  }
}

// ---------------- combine partials + epilogue ----------------
__global__ __launch_bounds__(256) void reduce_kernel(
    const float* __restrict__ part, const float* __restrict__ scales,
    const float* __restrict__ bias, float* __restrict__ out, int ks) {
  const int m = blockIdx.y;
  const int c4 = blockIdx.x * 256 + threadIdx.x;
  if (c4 >= N_DIM / 4) return;
  const size_t n = (size_t)c4 * 4;
  const float* p = part + (size_t)m * N_DIM + n;
  float4 s = *(const float4*)(p);
  for (int z = 1; z < ks; ++z) {
    float4 q = *(const float4*)(p + (size_t)z * PART_ELEMS);
    s.x += q.x; s.y += q.y; s.z += q.z; s.w += q.w;
  }
  float4 sc = *(const float4*)(scales + n);
  float4 bi = *(const float4*)(bias + n);
  float4 r;
  r.x = sc.x * s.x + bi.x;
  r.y = sc.y * s.y + bi.y;
  r.z = sc.z * s.z + bi.z;
  r.w = sc.w * s.w + bi.w;
  *(float4*)(out + (size_t)m * N_DIM + n) = r;
}

// ---------------- insurance path if ws is tiny ----------------
__global__ __launch_bounds__(256) void naive_kernel(
    const float* __restrict__ x, const int* __restrict__ wq,
    const float* __restrict__ scales, const float* __restrict__ bias,
    float* __restrict__ out) {
  const int n = blockIdx.x * 256 + threadIdx.x;
  const int m = blockIdx.y;
  const float* xr = x + (size_t)m * K_DIM;
  const int* wr = wq + (size_t)n * K_DIM;
  float s = 0.f;
  for (int k = 0; k < K_DIM; k += 4) {
    float4 xv = *(const float4*)(xr + k);
    int4  wv = *(const int4*)(wr + k);
    s += xv.x * (float)wv.x + xv.y * (float)wv.y +
         xv.z * (float)wv.z + xv.w * (float)wv.w;
  }
  out[(size_t)m * N_DIM + n] = scales[n] * s + bias[n];
}

extern "C" void kernel_launch(void* const* d_in, const int* in_sizes, int n_in,
                              void* d_out, int out_size, void* d_ws, size_t ws_size,
                              hipStream_t stream) {
  const float* x      = (const float*)d_in[0];
  const int* wq       = (const int*)d_in[1];
  const float* scales = (const float*)d_in[2];
  const float* bias   = (const float*)d_in[3];
  float* out          = (float*)d_out;

  const size_t need4 = (size_t)XP_BYTES + 4 * PART_ELEMS * sizeof(float);
  const size_t need2 = (size_t)XP_BYTES + 2 * PART_ELEMS * sizeof(float);
  int ks = (ws_size >= need4) ? 4 : (ws_size >= need2) ? 2
         : (ws_size >= (size_t)XP_BYTES) ? 1 : 0;
  if (ks == 0) {
    naive_kernel<<<dim3(N_DIM / 256, M_ROWS), 256, 0, stream>>>(x, wq, scales, bias, out);
    return;
  }
  unsigned short* xp = (unsigned short*)d_ws;
  float* part        = (float*)((char*)d_ws + XP_BYTES);

  pack_x_kernel<<<256, 256, 0, stream>>>(x, xp);
  gemm1w_kernel<<<dim3(NT16, ks), 64, 0, stream>>>(
      xp, wq, scales, bias, ks == 1 ? out : part, ks);
  if (ks > 1)
    reduce_kernel<<<dim3((N_DIM / 4 + 255) / 256, M_ROWS), 256, 0, stream>>>(
        part, scales, bias, out, ks);
}

// Round 5
// 54.414 us; speedup vs baseline: 2.1700x; 1.2032x over previous
//
#include <hip/hip_runtime.h>
#include <stdint.h>

// y[m][n] = scales[n] * sum_k x[m][k]*W[n][k] + bias[n]
// M=128, K=4096, N=11008. x fp32; W int8-valued int32 [N][K]; out fp32.
//
// Round-5 structure (fix r4's serialized A-loads: A via LDS DMA):
//   pack_x: x fp32 -> bf16 in MFMA A-frag order into ws (1 MiB, L2-resident).
//   gemm4w: 4 waves/block, each wave = FULL M (128) x 16 cols -> block BN=64.
//           No M-split across waves (would double B traffic, r3's disease).
//           A chunk (16 KiB bf16) staged once per block via global_load_lds,
//           double-buffered (32 KiB LDS) -> ds_read_b128 replaces the
//           serialized L2 loads that made r4 latency-bound. B int32 direct
//           to regs, double-buffered, issued before compute. One barrier
//           per chunk. K split 4 -> 688 blocks (~2.7/CU co-resident).
//   reduce: out = scales*(sum of 4 partials) + bias (deterministic).

#define M_ROWS 128
#define K_DIM  4096
#define N_DIM  11008
#define CHUNKS 64                       // K chunks of 64
#define NT64   (N_DIM / 64)             // 172 block n-tiles
#define XP_BYTES (M_ROWS * K_DIM * 2)   // 1 MiB packed bf16 x
#define PART_ELEMS ((size_t)M_ROWS * (size_t)N_DIM)

typedef __attribute__((ext_vector_type(8))) short bf16x8;
typedef __attribute__((ext_vector_type(4))) float f32x4;
typedef const unsigned __attribute__((address_space(1)))* gas1_t;
typedef unsigned __attribute__((address_space(3)))* las3_t;

__device__ __forceinline__ unsigned bf16_rn(float f) {
  unsigned u = __float_as_uint(f);
  return (u + 0x7FFFu + ((u >> 16) & 1u)) >> 16;   // round-to-nearest-even
}
// two exact int->f32, pack top halves into 2xbf16 (truncate = exact, |w|<=128)
__device__ __forceinline__ unsigned pk2(int a, int b) {
  unsigned lo = __float_as_uint((float)a), hi = __float_as_uint((float)b);
#if __has_builtin(__builtin_amdgcn_perm)
  return __builtin_amdgcn_perm(hi, lo, 0x07060302u);
#else
  return (hi & 0xFFFF0000u) | (lo >> 16);
#endif
}

__device__ __forceinline__ void gload_lds16(const void* g, void* lds) {
#if __has_builtin(__builtin_amdgcn_global_load_lds)
  // generic LDS pointer low 32 bits == LDS byte offset (validated in r2: passed)
  __builtin_amdgcn_global_load_lds((gas1_t)g, (las3_t)(size_t)(unsigned)(size_t)lds,
                                   16, 0, 0);
#else
  *(uint4*)lds = *(const uint4*)g;  // synchronous fallback (correct)
#endif
}

// ---------------- pack x: fp32 -> bf16 in A-frag order ----------------
// Chunk kk = 16 KiB: 16B unit u = (mf*2 + s)*64 + lane
// frag (mf,s): lane l holds x[16*mf + (l&15)][kk*64 + s*32 + 8*(l>>4) + j]
__global__ __launch_bounds__(256) void pack_x_kernel(
    const float* __restrict__ x, unsigned short* __restrict__ xp) {
  int tid  = blockIdx.x * 256 + threadIdx.x;   // 65536 threads
  int lane = tid & 63;
  int h    = (tid >> 6) & 1;
  int mf   = (tid >> 7) & 7;
  int kk   = tid >> 10;
  int m     = mf * 16 + (lane & 15);
  int kbase = kk * 64 + h * 32 + ((lane >> 4) * 8);
  const float* src = x + (size_t)m * K_DIM + kbase;
  float4 f0 = *(const float4*)(src);
  float4 f1 = *(const float4*)(src + 4);
  float v[8] = {f0.x, f0.y, f0.z, f0.w, f1.x, f1.y, f1.z, f1.w};
  unsigned po[4];
#pragma unroll
  for (int i = 0; i < 4; ++i)
    po[i] = bf16_rn(v[2 * i]) | (bf16_rn(v[2 * i + 1]) << 16);
  *(uint4*)(xp + (size_t)tid * 8) = *(uint4*)po;
}

// ---------------- 4-wave GEMM: block BM=128 x BN=64, wave = 128x16 ----------
struct BReg { uint4 v[4]; };   // one chunk of B per lane: 16 ints

__global__ __launch_bounds__(256, 3) void gemm4w_kernel(
    const unsigned short* __restrict__ xp,
    const int* __restrict__ wq,
    const float* __restrict__ scales,
    const float* __restrict__ bias,
    float* __restrict__ dst,          // ks==1: out, else partials
    int ks) {
  __shared__ char As0[16384];
  __shared__ char As1[16384];

  const int tid  = threadIdx.x;
  const int lane = tid & 63;
  const int w    = tid >> 6;          // wave 0..3 -> cols [16w, 16w+16)
  const int nt   = blockIdx.x;        // 0..171
  const int kz   = blockIdx.y;        // 0..ks-1
  const int cpb  = CHUNKS / ks;       // 16 for ks=4 (even for ks=1,2,4)
  const int kk0  = kz * cpb;
  const size_t n0 = (size_t)nt * 64 + (size_t)w * 16;
  const int l15 = lane & 15, lh = lane >> 4;

  // A staging: block covers 16 KiB/chunk; thread stages 4x16B, lane-linear
  const char* agp = (const char*)xp + (size_t)kk0 * 16384 + tid * 16;
  // B: row n0 + l15; ints at (kk0+t)*64 + s*32 + lh*8 .. +8
  const int* bptr = wq + (n0 + (size_t)l15) * K_DIM + (size_t)kk0 * 64 + lh * 8;

  f32x4 acc[8];
  {
    f32x4 z = {0.f, 0.f, 0.f, 0.f};
#pragma unroll
    for (int i = 0; i < 8; ++i) acc[i] = z;
  }

  auto STAGE = [&](int t, char* buf) {
#pragma unroll
    for (int i = 0; i < 4; ++i)
      gload_lds16(agp + (size_t)t * 16384 + (size_t)i * 4096,
                  buf + tid * 16 + i * 4096);
  };
  auto LOADB = [&](int t, BReg& R) {
    const int* bp = bptr + t * 64;
    R.v[0] = *(const uint4*)(bp);
    R.v[1] = *(const uint4*)(bp + 4);
    R.v[2] = *(const uint4*)(bp + 32);
    R.v[3] = *(const uint4*)(bp + 36);
  };
  auto COMP = [&](const char* ab, BReg& R) {
    bf16x8 cv[2];
#pragma unroll
    for (int s = 0; s < 2; ++s) {
      union { unsigned u[4]; bf16x8 b; } c;
      c.u[0] = pk2((int)R.v[s * 2].x,     (int)R.v[s * 2].y);
      c.u[1] = pk2((int)R.v[s * 2].z,     (int)R.v[s * 2].w);
      c.u[2] = pk2((int)R.v[s * 2 + 1].x, (int)R.v[s * 2 + 1].y);
      c.u[3] = pk2((int)R.v[s * 2 + 1].z, (int)R.v[s * 2 + 1].w);
      cv[s] = c.b;
    }
#pragma unroll
    for (int mf = 0; mf < 8; ++mf)
#pragma unroll
      for (int s = 0; s < 2; ++s) {
        bf16x8 a = *(const bf16x8*)(ab + (mf * 2 + s) * 1024 + lane * 16);
        acc[mf] = __builtin_amdgcn_mfma_f32_16x16x32_bf16(a, cv[s], acc[mf], 0, 0, 0);
      }
  };

  BReg R0, R1;
  STAGE(0, As0);
  LOADB(0, R0);
  __syncthreads();                       // A0 resident, B0 in flight->regs

#pragma unroll 1
  for (int tt = 0; tt < cpb; tt += 2) {
    STAGE(tt + 1, As1);                  // cpb even -> tt+1 always valid
    LOADB(tt + 1, R1);
    COMP(As0, R0);
    __syncthreads();                     // As1 resident; As0 free
    if (tt + 2 < cpb) { STAGE(tt + 2, As0); LOADB(tt + 2, R0); }
    COMP(As1, R1);
    __syncthreads();                     // As0 resident; As1 free
  }

  // epilogue: m = mf*16 + lh*4 + r ; n = n0 + l15
  if (ks == 1) {
    const size_t n = n0 + (size_t)l15;
    const float sc = scales[n], bi = bias[n];
#pragma unroll
    for (int mf = 0; mf < 8; ++mf) {
      const int mb = mf * 16 + lh * 4;
#pragma unroll
      for (int r = 0; r < 4; ++r)
        dst[(size_t)(mb + r) * N_DIM + n] = sc * acc[mf][r] + bi;
    }
  } else {
    float* pb = dst + (size_t)kz * PART_ELEMS + n0 + l15;
#pragma unroll
    for (int mf = 0; mf < 8; ++mf) {
      const int mb = mf * 16 + lh * 4;
#pragma unroll
      for (int r = 0; r < 4; ++r)
        pb[(size_t)(mb + r) * N_DIM] = acc[mf][r];
    }
  }
}

// ---------------- combine partials + epilogue ----------------
__global__ __launch_bounds__(256) void reduce_kernel(
    const float* __restrict__ part, const float* __restrict__ scales,
    const float* __restrict__ bias, float* __restrict__ out, int ks) {
  const int m = blockIdx.y;
  const int c4 = blockIdx.x * 256 + threadIdx.x;
  if (c4 >= N_DIM / 4) return;
  const size_t n = (size_t)c4 * 4;
  const float* p = part + (size_t)m * N_DIM + n;
  float4 s = *(const float4*)(p);
  for (int z = 1; z < ks; ++z) {
    float4 q = *(const float4*)(p + (size_t)z * PART_ELEMS);
    s.x += q.x; s.y += q.y; s.z += q.z; s.w += q.w;
  }
  float4 sc = *(const float4*)(scales + n);
  float4 bi = *(const float4*)(bias + n);
  float4 r;
  r.x = sc.x * s.x + bi.x;
  r.y = sc.y * s.y + bi.y;
  r.z = sc.z * s.z + bi.z;
  r.w = sc.w * s.w + bi.w;
  *(float4*)(out + (size_t)m * N_DIM + n) = r;
}

// ---------------- insurance path if ws is tiny ----------------
__global__ __launch_bounds__(256) void naive_kernel(
    const float* __restrict__ x, const int* __restrict__ wq,
    const float* __restrict__ scales, const float* __restrict__ bias,
    float* __restrict__ out) {
  const int n = blockIdx.x * 256 + threadIdx.x;
  const int m = blockIdx.y;
  const float* xr = x + (size_t)m * K_DIM;
  const int* wr = wq + (size_t)n * K_DIM;
  float s = 0.f;
  for (int k = 0; k < K_DIM; k += 4) {
    float4 xv = *(const float4*)(xr + k);
    int4  wv = *(const int4*)(wr + k);
    s += xv.x * (float)wv.x + xv.y * (float)wv.y +
         xv.z * (float)wv.z + xv.w * (float)wv.w;
  }
  out[(size_t)m * N_DIM + n] = scales[n] * s + bias[n];
}

extern "C" void kernel_launch(void* const* d_in, const int* in_sizes, int n_in,
                              void* d_out, int out_size, void* d_ws, size_t ws_size,
                              hipStream_t stream) {
  const float* x      = (const float*)d_in[0];
  const int* wq       = (const int*)d_in[1];
  const float* scales = (const float*)d_in[2];
  const float* bias   = (const float*)d_in[3];
  float* out          = (float*)d_out;

  const size_t need4 = (size_t)XP_BYTES + 4 * PART_ELEMS * sizeof(float);
  const size_t need2 = (size_t)XP_BYTES + 2 * PART_ELEMS * sizeof(float);
  int ks = (ws_size >= need4) ? 4 : (ws_size >= need2) ? 2
         : (ws_size >= (size_t)XP_BYTES) ? 1 : 0;
  if (ks == 0) {
    naive_kernel<<<dim3(N_DIM / 256, M_ROWS), 256, 0, stream>>>(x, wq, scales, bias, out);
    return;
  }
  unsigned short* xp = (unsigned short*)d_ws;
  float* part        = (float*)((char*)d_ws + XP_BYTES);

  pack_x_kernel<<<256, 256, 0, stream>>>(x, xp);
  gemm4w_kernel<<<dim3(NT64, ks), 256, 0, stream>>>(
      xp, wq, scales, bias, ks == 1 ? out : part, ks);
  if (ks > 1)
    reduce_kernel<<<dim3((N_DIM / 4 + 255) / 256, M_ROWS), 256, 0, stream>>>(
        part, scales, bias, out, ks);
}

// Round 6
// 52.984 us; speedup vs baseline: 2.2285x; 1.0270x over previous
//
#include <hip/hip_runtime.h>
#include <stdint.h>

// y[m][n] = scales[n] * sum_k x[m][k]*W[n][k] + bias[n]
// M=128, K=4096, N=11008. x fp32; W int8-valued int32 [N][K]; out fp32.
//
// Round-6 structure (r5 + split-barrier counted-vmcnt K-loop):
//   pack_x: x fp32 -> bf16 in MFMA A-frag order into ws (1 MiB, L2-resident).
//   gemm4w: 4 waves/block, each wave = FULL M (128) x 16 cols -> block BN=64.
//           A chunk staged via global_load_lds (dbuf 32 KiB); B int32 -> regs
//           (dbuf), converted in-reg to bf16 (exact). K split 4 -> 688 blocks.
//           K-loop uses raw s_barrier + s_waitcnt vmcnt(8): each phase issues
//           exactly 8 vmem ops (4 B loads + 4 LDS-DMAs), so vmcnt(8) waits
//           for the PREVIOUS phase's ops only -- prefetch stays in flight
//           across the barrier (T3/T4-lite), unlike __syncthreads' vmcnt(0)
//           drain which exposed L3 latency every chunk in r5.
//   reduce: out = scales*(sum of 4 partials) + bias (deterministic).

#define M_ROWS 128
#define K_DIM  4096
#define N_DIM  11008
#define CHUNKS 64                       // K chunks of 64
#define NT64   (N_DIM / 64)             // 172 block n-tiles
#define XP_BYTES (M_ROWS * K_DIM * 2)   // 1 MiB packed bf16 x
#define PART_ELEMS ((size_t)M_ROWS * (size_t)N_DIM)

typedef __attribute__((ext_vector_type(8))) short bf16x8;
typedef __attribute__((ext_vector_type(4))) float f32x4;
typedef const unsigned __attribute__((address_space(1)))* gas1_t;
typedef unsigned __attribute__((address_space(3)))* las3_t;

__device__ __forceinline__ unsigned bf16_rn(float f) {
  unsigned u = __float_as_uint(f);
  return (u + 0x7FFFu + ((u >> 16) & 1u)) >> 16;   // round-to-nearest-even
}
// two exact int->f32, pack top halves into 2xbf16 (truncate = exact, |w|<=128)
__device__ __forceinline__ unsigned pk2(int a, int b) {
  unsigned lo = __float_as_uint((float)a), hi = __float_as_uint((float)b);
#if __has_builtin(__builtin_amdgcn_perm)
  return __builtin_amdgcn_perm(hi, lo, 0x07060302u);
#else
  return (hi & 0xFFFF0000u) | (lo >> 16);
#endif
}

__device__ __forceinline__ void gload_lds16(const void* g, void* lds) {
#if __has_builtin(__builtin_amdgcn_global_load_lds)
  // generic LDS pointer low 32 bits == LDS byte offset (validated r2-r5)
  __builtin_amdgcn_global_load_lds((gas1_t)g, (las3_t)(size_t)(unsigned)(size_t)lds,
                                   16, 0, 0);
#else
  *(uint4*)lds = *(const uint4*)g;  // synchronous fallback (correct)
#endif
}

// barrier only (no drain): buffer hand-off where no new data is consumed
#define BAR()   asm volatile("s_barrier" ::: "memory")
// wait for all but the newest 8 vmem ops (= this phase's 4 DMA + 4 B loads),
// then barrier: previous phase's A-DMA is LDS-resident for ALL waves.
#define WBAR8() asm volatile("s_waitcnt vmcnt(8)\n\ts_barrier" ::: "memory")
#define WBAR0() asm volatile("s_waitcnt vmcnt(0)\n\ts_barrier" ::: "memory")

// ---------------- pack x: fp32 -> bf16 in A-frag order ----------------
// Chunk kk = 16 KiB: 16B unit u = (mf*2 + s)*64 + lane
// frag (mf,s): lane l holds x[16*mf + (l&15)][kk*64 + s*32 + 8*(l>>4) + j]
__global__ __launch_bounds__(256) void pack_x_kernel(
    const float* __restrict__ x, unsigned short* __restrict__ xp) {
  int tid  = blockIdx.x * 256 + threadIdx.x;   // 65536 threads
  int lane = tid & 63;
  int h    = (tid >> 6) & 1;
  int mf   = (tid >> 7) & 7;
  int kk   = tid >> 10;
  int m     = mf * 16 + (lane & 15);
  int kbase = kk * 64 + h * 32 + ((lane >> 4) * 8);
  const float* src = x + (size_t)m * K_DIM + kbase;
  float4 f0 = *(const float4*)(src);
  float4 f1 = *(const float4*)(src + 4);
  float v[8] = {f0.x, f0.y, f0.z, f0.w, f1.x, f1.y, f1.z, f1.w};
  unsigned po[4];
#pragma unroll
  for (int i = 0; i < 4; ++i)
    po[i] = bf16_rn(v[2 * i]) | (bf16_rn(v[2 * i + 1]) << 16);
  *(uint4*)(xp + (size_t)tid * 8) = *(uint4*)po;
}

// ---------------- 4-wave GEMM: block BM=128 x BN=64, wave = 128x16 ----------
struct BReg { uint4 v[4]; };   // one chunk of B per lane: 16 ints

__global__ __launch_bounds__(256, 3) void gemm4w_kernel(
    const unsigned short* __restrict__ xp,
    const int* __restrict__ wq,
    const float* __restrict__ scales,
    const float* __restrict__ bias,
    float* __restrict__ dst,          // ks==1: out, else partials
    int ks) {
  __shared__ char As0[16384];
  __shared__ char As1[16384];

  const int tid  = threadIdx.x;
  const int lane = tid & 63;
  const int w    = tid >> 6;          // wave 0..3 -> cols [16w, 16w+16)
  const int nt   = blockIdx.x;        // 0..171
  const int kz   = blockIdx.y;        // 0..ks-1
  const int cpb  = CHUNKS / ks;       // 16 for ks=4 (even, >=4)
  const int kk0  = kz * cpb;
  const size_t n0 = (size_t)nt * 64 + (size_t)w * 16;
  const int l15 = lane & 15, lh = lane >> 4;

  // A staging: block covers 16 KiB/chunk; thread stages 4x16B, lane-linear
  const char* agp = (const char*)xp + (size_t)kk0 * 16384 + tid * 16;
  // B: row n0 + l15; ints at (kk0+t)*64 + s*32 + lh*8 .. +8
  const int* bptr = wq + (n0 + (size_t)l15) * K_DIM + (size_t)kk0 * 64 + lh * 8;

  f32x4 acc[8];
  {
    f32x4 z = {0.f, 0.f, 0.f, 0.f};
#pragma unroll
    for (int i = 0; i < 8; ++i) acc[i] = z;
  }

  auto STAGE = [&](int t, char* buf) {
#pragma unroll
    for (int i = 0; i < 4; ++i)
      gload_lds16(agp + (size_t)t * 16384 + (size_t)i * 4096,
                  buf + tid * 16 + i * 4096);
  };
  auto LOADB = [&](int t, BReg& R) {
    const int* bp = bptr + t * 64;
    R.v[0] = *(const uint4*)(bp);
    R.v[1] = *(const uint4*)(bp + 4);
    R.v[2] = *(const uint4*)(bp + 32);
    R.v[3] = *(const uint4*)(bp + 36);
  };
  auto COMP = [&](const char* ab, BReg& R) {
    bf16x8 cv[2];
#pragma unroll
    for (int s = 0; s < 2; ++s) {
      union { unsigned u[4]; bf16x8 b; } c;
      c.u[0] = pk2((int)R.v[s * 2].x,     (int)R.v[s * 2].y);
      c.u[1] = pk2((int)R.v[s * 2].z,     (int)R.v[s * 2].w);
      c.u[2] = pk2((int)R.v[s * 2 + 1].x, (int)R.v[s * 2 + 1].y);
      c.u[3] = pk2((int)R.v[s * 2 + 1].z, (int)R.v[s * 2 + 1].w);
      cv[s] = c.b;
    }
#pragma unroll
    for (int mf = 0; mf < 8; ++mf)
#pragma unroll
      for (int s = 0; s < 2; ++s) {
        bf16x8 a = *(const bf16x8*)(ab + (mf * 2 + s) * 1024 + lane * 16);
        acc[mf] = __builtin_amdgcn_mfma_f32_16x16x32_bf16(a, cv[s], acc[mf], 0, 0, 0);
      }
  };

  // prologue: issue chunk 0 (8 vmem ops in flight)
  BReg R0, R1;
  STAGE(0, As0);
  LOADB(0, R0);

  // steady state: every phase issues exactly 8 vmem ops, then vmcnt(8)
  // waits for the PREVIOUS phase's 8 -> prefetch spans a full chunk time.
#pragma unroll 1
  for (int t = 0; t < cpb - 2; t += 2) {
    LOADB(t + 1, R1);       // regs: wave-private, safe before barrier
    BAR();                  // all waves done COMP(t-1) -> As1 free
    STAGE(t + 1, As1);
    WBAR8();                // A(t),B(t) landed; A(t) resident for all waves
    COMP(As0, R0);

    LOADB(t + 2, R0);
    BAR();                  // all waves done COMP(t) -> As0 free
    STAGE(t + 2, As0);
    WBAR8();                // A(t+1),B(t+1) resident
    COMP(As1, R1);
  }
  // tail: chunks cpb-2, cpb-1
  LOADB(cpb - 1, R1);
  BAR();
  STAGE(cpb - 1, As1);
  WBAR8();
  COMP(As0, R0);
  WBAR0();                  // drain last chunk
  COMP(As1, R1);

  // epilogue: m = mf*16 + lh*4 + r ; n = n0 + l15
  if (ks == 1) {
    const size_t n = n0 + (size_t)l15;
    const float sc = scales[n], bi = bias[n];
#pragma unroll
    for (int mf = 0; mf < 8; ++mf) {
      const int mb = mf * 16 + lh * 4;
#pragma unroll
      for (int r = 0; r < 4; ++r)
        dst[(size_t)(mb + r) * N_DIM + n] = sc * acc[mf][r] + bi;
    }
  } else {
    float* pb = dst + (size_t)kz * PART_ELEMS + n0 + l15;
#pragma unroll
    for (int mf = 0; mf < 8; ++mf) {
      const int mb = mf * 16 + lh * 4;
#pragma unroll
      for (int r = 0; r < 4; ++r)
        pb[(size_t)(mb + r) * N_DIM] = acc[mf][r];
    }
  }
}

// ---------------- combine partials + epilogue ----------------
__global__ __launch_bounds__(256) void reduce_kernel(
    const float* __restrict__ part, const float* __restrict__ scales,
    const float* __restrict__ bias, float* __restrict__ out, int ks) {
  const int m = blockIdx.y;
  const int c4 = blockIdx.x * 256 + threadIdx.x;
  if (c4 >= N_DIM / 4) return;
  const size_t n = (size_t)c4 * 4;
  const float* p = part + (size_t)m * N_DIM + n;
  float4 s = *(const float4*)(p);
  for (int z = 1; z < ks; ++z) {
    float4 q = *(const float4*)(p + (size_t)z * PART_ELEMS);
    s.x += q.x; s.y += q.y; s.z += q.z; s.w += q.w;
  }
  float4 sc = *(const float4*)(scales + n);
  float4 bi = *(const float4*)(bias + n);
  float4 r;
  r.x = sc.x * s.x + bi.x;
  r.y = sc.y * s.y + bi.y;
  r.z = sc.z * s.z + bi.z;
  r.w = sc.w * s.w + bi.w;
  *(float4*)(out + (size_t)m * N_DIM + n) = r;
}

// ---------------- insurance path if ws is tiny ----------------
__global__ __launch_bounds__(256) void naive_kernel(
    const float* __restrict__ x, const int* __restrict__ wq,
    const float* __restrict__ scales, const float* __restrict__ bias,
    float* __restrict__ out) {
  const int n = blockIdx.x * 256 + threadIdx.x;
  const int m = blockIdx.y;
  const float* xr = x + (size_t)m * K_DIM;
  const int* wr = wq + (size_t)n * K_DIM;
  float s = 0.f;
  for (int k = 0; k < K_DIM; k += 4) {
    float4 xv = *(const float4*)(xr + k);
    int4  wv = *(const int4*)(wr + k);
    s += xv.x * (float)wv.x + xv.y * (float)wv.y +
         xv.z * (float)wv.z + xv.w * (float)wv.w;
  }
  out[(size_t)m * N_DIM + n] = scales[n] * s + bias[n];
}

extern "C" void kernel_launch(void* const* d_in, const int* in_sizes, int n_in,
                              void* d_out, int out_size, void* d_ws, size_t ws_size,
                              hipStream_t stream) {
  const float* x      = (const float*)d_in[0];
  const int* wq       = (const int*)d_in[1];
  const float* scales = (const float*)d_in[2];
  const float* bias   = (const float*)d_in[3];
  float* out          = (float*)d_out;

  const size_t need4 = (size_t)XP_BYTES + 4 * PART_ELEMS * sizeof(float);
  const size_t need2 = (size_t)XP_BYTES + 2 * PART_ELEMS * sizeof(float);
  int ks = (ws_size >= need4) ? 4 : (ws_size >= need2) ? 2
         : (ws_size >= (size_t)XP_BYTES) ? 1 : 0;
  if (ks == 0) {
    naive_kernel<<<dim3(N_DIM / 256, M_ROWS), 256, 0, stream>>>(x, wq, scales, bias, out);
    return;
  }
  unsigned short* xp = (unsigned short*)d_ws;
  float* part        = (float*)((char*)d_ws + XP_BYTES);

  pack_x_kernel<<<256, 256, 0, stream>>>(x, xp);
  gemm4w_kernel<<<dim3(NT64, ks), 256, 0, stream>>>(
      xp, wq, scales, bias, ks == 1 ? out : part, ks);
  if (ks > 1)
    reduce_kernel<<<dim3((N_DIM / 4 + 255) / 256, M_ROWS), 256, 0, stream>>>(
        part, scales, bias, out, ks);
}